// Round 7
// baseline (329.725 us; speedup 1.0000x reference)
//
#include <hip/hip_runtime.h>
#include <math.h>

typedef __bf16 bf16_t;
typedef bf16_t bf16x8 __attribute__((ext_vector_type(8)));
typedef float  f32x4  __attribute__((ext_vector_type(4)));
typedef float  f32x16 __attribute__((ext_vector_type(16)));

#define PI_F 3.14159265358979323846f

constexpr int H = 64, W = 64, Q = 65536;
constexpr int C = 256, CF = 128;
constexpr int MROWS = Q * 4;   // 262144 rows
constexpr int QPB = 32;        // queries per block (fused + mlp tile)
constexpr int PADC = 264;      // fused-path LDS row stride

// ---------------- prep kernels ----------------

__global__ void transpose_cvt_kernel(const float* __restrict__ src, bf16_t* __restrict__ dst, int Crows) {
    __shared__ float tile[32][33];
    int bx = blockIdx.x * 32;
    int by = blockIdx.y * 32;
    int tx = threadIdx.x & 31;
    int ty = threadIdx.x >> 5;
#pragma unroll
    for (int i = 0; i < 4; i++)
        tile[ty + i * 8][tx] = src[(by + ty + i * 8) * 4096 + bx + tx];
    __syncthreads();
#pragma unroll
    for (int i = 0; i < 4; i++)
        dst[(bx + ty + i * 8) * Crows + by + tx] = (bf16_t)tile[tx][ty + i * 8];
}

__global__ void cvt_w_kernel(const float* __restrict__ w1, const float* __restrict__ w2,
                             bf16_t* __restrict__ w1b, bf16_t* __restrict__ w2b) {
    int i = blockIdx.x * 256 + threadIdx.x;
    w1b[i] = (bf16_t)w1[i];
    w2b[i] = (bf16_t)w2[i];
}

__global__ void pack_tab_kernel(const float* __restrict__ wcf, const float* __restrict__ wph,
                                float4* __restrict__ wtab) {
    int k = threadIdx.x;
    float4 v;
    v.x = wcf[k * 2 + 0]; v.y = wcf[k * 2 + 1];
    v.z = wph[k * 2 + 0]; v.w = wph[k * 2 + 1];
    wtab[k] = v;
}

// w3 [3][256] -> w3p [16][256] bf16, rows 3..15 zero
__global__ void cvt_w3_kernel(const float* __restrict__ w3, bf16_t* __restrict__ w3p) {
    int k = threadIdx.x;
#pragma unroll
    for (int n = 0; n < 16; n++)
        w3p[n * 256 + k] = (n < 3) ? (bf16_t)w3[n * 256 + k] : (bf16_t)0.f;
}

// =====================================================================
// SPLIT PATH
// X file layout: [row][512 B], 16-B granules XOR-swizzled: g_file = g ^ (row&31)
// =====================================================================

// ---- K1: feature generation (no LDS, no barriers) ----
__global__ __launch_bounds__(256)
void feat_kernel(const bf16_t* __restrict__ coefT,  // [4096][256]
                 const bf16_t* __restrict__ freqT,  // [4096][128]
                 const float4* __restrict__ wtab,   // [128]
                 const float* __restrict__ coord,
                 const float* __restrict__ cell,
                 char* __restrict__ xf,             // [MROWS][512 B] swizzled
                 float* __restrict__ areaW)         // [MROWS]
{
    const int t    = threadIdx.x;
    const int rowL = t >> 2;
    const int t4   = t & 3;
    const int row  = blockIdx.x * 64 + rowL;
    const int q    = row >> 2;
    const int o    = row & 3;

    const float c0  = coord[q * 2 + 0];
    const float c1  = coord[q * 2 + 1];
    const float rc0 = cell[q * 2 + 0] * (float)H;
    const float rc1 = cell[q * 2 + 1] * (float)W;
    const float vx = (o & 2) ? 1.f : -1.f;
    const float vy = (o & 1) ? 1.f : -1.f;
    const float EPS = 1e-6f;
    float g0 = fminf(fmaxf(c0 + vx * (1.f / H) + EPS, -1.f + EPS), 1.f - EPS);
    float g1 = fminf(fmaxf(c1 + vy * (1.f / W) + EPS, -1.f + EPS), 1.f - EPS);
    int iy = (int)floorf(((g0 + 1.f) * (float)H - 1.f) * 0.5f + 0.5f);
    iy = min(max(iy, 0), H - 1);
    int ix = (int)floorf(((g1 + 1.f) * (float)W - 1.f) * 0.5f + 0.5f);
    ix = min(max(ix, 0), W - 1);
    const float rel0 = (c0 - (-1.f + (2.f * (float)iy + 1.f) / (float)H)) * (float)H;
    const float rel1 = (c1 - (-1.f + (2.f * (float)ix + 1.f) / (float)W)) * (float)W;
    if (t4 == 0) areaW[row] = fabsf(rel0 * rel1) + 1e-9f;

    const int pix = iy * W + ix;
    const bf16_t* fq = freqT + pix * CF;
    const bf16_t* cf = coefT + pix * C;
    const int k0 = t4 * 32;

    bf16x8 fqv[4], ccv[4], csv[4];
#pragma unroll
    for (int i = 0; i < 4; i++) {
        fqv[i] = *(const bf16x8*)(fq + k0 + i * 8);
        ccv[i] = *(const bf16x8*)(cf + k0 + i * 8);
        csv[i] = *(const bf16x8*)(cf + 128 + k0 + i * 8);
    }
    const int rsw = row & 31;
    char* xrow = xf + (size_t)row * 512;
#pragma unroll
    for (int i = 0; i < 4; i++) {
        bf16x8 vc, vs;
#pragma unroll
        for (int j = 0; j < 8; j++) {
            const int k = k0 + i * 8 + j;
            const float4 tv = wtab[k];
            const float proj = rel0 * tv.x + rel1 * tv.y;
            const float ph   = rc0 * tv.z + rc1 * tv.w;
            const float m = (float)fqv[i][j] * proj + ph;
            float s, cst;
            __sincosf(PI_F * m, &s, &cst);
            vc[j] = (bf16_t)((float)ccv[i][j] * cst);
            vs[j] = (bf16_t)((float)csv[i][j] * s);
        }
        const int gc = t4 * 4 + i;        // cos granule (cols k0..k0+31)
        const int gs = 16 + t4 * 4 + i;   // sin granule
        *(bf16x8*)(xrow + ((gc ^ rsw) << 4)) = vc;
        *(bf16x8*)(xrow + ((gs ^ rsw) << 4)) = vs;
    }
}

// ---- K2: MLP + combine. 128-row tile staged via global_load_lds ----

#define LOADBM(dst, Wptr, kb) {                                                                \
    dst[0] = *(const bf16x8*)((Wptr) + (wv * 32 + l15) * 256 + (kb) * 32 + l16 * 8);           \
    dst[1] = *(const bf16x8*)((Wptr) + (wv * 32 + 16 + l15) * 256 + (kb) * 32 + l16 * 8); }

__global__ __launch_bounds__(512, 4)
void mlp_kernel(const char* __restrict__ xf,        // swizzled X file
                const bf16_t* __restrict__ w1b,
                const bf16_t* __restrict__ w2b,
                const bf16_t* __restrict__ w3p,     // [16][256]
                const float* __restrict__ areaW,
                const float* __restrict__ img,
                const float* __restrict__ coord,
                const float* __restrict__ b1,
                const float* __restrict__ b2,
                const float* __restrict__ b3,
                float* __restrict__ out)
{
    extern __shared__ char smem[];
    char*  bufc   = smem;                    // 65536 B: swizzled [128][512 B]
    float* predsS = (float*)(smem + 65536);  // [128][3]

    const int t    = threadIdx.x;
    const int lane = t & 63;
    const int wv   = t >> 6;     // wave 0..7 -> 32-col stripe
    const int l15  = lane & 15;
    const int l16  = lane >> 4;

    const char* xtile = xf + (size_t)blockIdx.x * (128 * 512);

    // async stage X tile (64 KB), linear byte-for-byte (file already swizzled)
#pragma unroll
    for (int r = 0; r < 8; r++) {
        const int off = r * 8192 + wv * 1024;
        __builtin_amdgcn_global_load_lds(
            (const __attribute__((address_space(1))) void*)(xtile + off + lane * 16),
            (__attribute__((address_space(3))) void*)(bufc + off),
            16, 0, 0);
    }

    bf16x8 b1q[8][2];
    LOADBM(b1q[0], w1b, 0);
    LOADBM(b1q[1], w1b, 1);
    __syncthreads();  // drains vmcnt(0): X tile resident

    // swizzled A-fragment read: rows rb+l15, k = kb*32 + l16*8
#define LDA(rb, kb) (*(const bf16x8*)(bufc + ((rb) + l15) * 512 +                              \
        (((((kb) * 4 + l16) ^ (((rb) + l15) & 31))) << 4)))

    // ---- layer 1 ----
    bf16x8 b2q[8][2];
    {
        f32x4 acc[8][2];
#pragma unroll
        for (int mi = 0; mi < 8; mi++)
#pragma unroll
            for (int nf = 0; nf < 2; nf++) {
                f32x4 z = {0.f, 0.f, 0.f, 0.f};
                acc[mi][nf] = z;
            }
#pragma unroll
        for (int kb = 0; kb < 8; kb++) {
            if (kb < 6) { LOADBM(b1q[kb + 2], w1b, kb + 2); }
            bf16x8 a[8];
#pragma unroll
            for (int mi = 0; mi < 8; mi++)
                a[mi] = LDA(mi * 16, kb);
#pragma unroll
            for (int mi = 0; mi < 8; mi++)
#pragma unroll
                for (int nf = 0; nf < 2; nf++)
                    acc[mi][nf] = __builtin_amdgcn_mfma_f32_16x16x32_bf16(a[mi], b1q[kb][nf], acc[mi][nf], 0, 0, 0);
        }
        LOADBM(b2q[0], w2b, 0);
        LOADBM(b2q[1], w2b, 1);
        __syncthreads();  // all reads of X done
#pragma unroll
        for (int nf = 0; nf < 2; nf++) {
            const int col = wv * 32 + nf * 16 + l15;
            const float bv = b1[col];
            const int gcol = col >> 3;
            const int grem = (col & 7) * 2;
#pragma unroll
            for (int mi = 0; mi < 8; mi++)
#pragma unroll
                for (int r = 0; r < 4; r++) {
                    const int row = mi * 16 + l16 * 4 + r;
                    *(bf16_t*)(bufc + row * 512 + ((gcol ^ (row & 31)) << 4) + grem) =
                        (bf16_t)fmaxf(acc[mi][nf][r] + bv, 0.f);
                }
        }
        __syncthreads();
    }

    // ---- layer 2 ----
    {
        f32x4 acc[8][2];
#pragma unroll
        for (int mi = 0; mi < 8; mi++)
#pragma unroll
            for (int nf = 0; nf < 2; nf++) {
                f32x4 z = {0.f, 0.f, 0.f, 0.f};
                acc[mi][nf] = z;
            }
#pragma unroll
        for (int kb = 0; kb < 8; kb++) {
            if (kb < 6) { LOADBM(b2q[kb + 2], w2b, kb + 2); }
            bf16x8 a[8];
#pragma unroll
            for (int mi = 0; mi < 8; mi++)
                a[mi] = LDA(mi * 16, kb);
#pragma unroll
            for (int mi = 0; mi < 8; mi++)
#pragma unroll
                for (int nf = 0; nf < 2; nf++)
                    acc[mi][nf] = __builtin_amdgcn_mfma_f32_16x16x32_bf16(a[mi], b2q[kb][nf], acc[mi][nf], 0, 0, 0);
        }
        __syncthreads();
#pragma unroll
        for (int nf = 0; nf < 2; nf++) {
            const int col = wv * 32 + nf * 16 + l15;
            const float bv = b2[col];
            const int gcol = col >> 3;
            const int grem = (col & 7) * 2;
#pragma unroll
            for (int mi = 0; mi < 8; mi++)
#pragma unroll
                for (int r = 0; r < 4; r++) {
                    const int row = mi * 16 + l16 * 4 + r;
                    *(bf16_t*)(bufc + row * 512 + ((gcol ^ (row & 31)) << 4) + grem) =
                        (bf16_t)fmaxf(acc[mi][nf][r] + bv, 0.f);
                }
        }
        __syncthreads();
    }

    // ---- layer 3: MFMA vs padded w3; wave wv handles rows wv*16.. ----
    {
        f32x4 acc3 = {0.f, 0.f, 0.f, 0.f};
#pragma unroll
        for (int kb = 0; kb < 8; kb++) {
            bf16x8 a = LDA(wv * 16, kb);
            bf16x8 b = *(const bf16x8*)(w3p + l15 * 256 + kb * 32 + l16 * 8);
            acc3 = __builtin_amdgcn_mfma_f32_16x16x32_bf16(a, b, acc3, 0, 0, 0);
        }
        if (l15 < 3) {
            const float bv = b3[l15];
#pragma unroll
            for (int r = 0; r < 4; r++) {
                const int row = wv * 16 + l16 * 4 + r;
                predsS[row * 3 + l15] = acc3[r] + bv;
            }
        }
    }
    __syncthreads();

    // ---- combine: 96 threads, one per (query, channel) ----
    if (t < 96) {
        const int ch = t >> 5;      // 0..2
        const int qL = t & 31;      // 0..31
        const int q  = blockIdx.x * QPB + qL;
        const int r0 = qL * 4;
        const float4 av = *(const float4*)(areaW + (size_t)blockIdx.x * 128 + r0);
        const float inv = 1.f / (av.x + av.y + av.z + av.w);
        const float wgt0 = av.w * inv, wgt1 = av.z * inv, wgt2 = av.y * inv, wgt3 = av.x * inv;
        const float ret = predsS[(r0 + 0) * 3 + ch] * wgt0 + predsS[(r0 + 1) * 3 + ch] * wgt1
                        + predsS[(r0 + 2) * 3 + ch] * wgt2 + predsS[(r0 + 3) * 3 + ch] * wgt3;
        const float c0 = coord[q * 2 + 0];
        const float c1 = coord[q * 2 + 1];
        float gy = fminf(fmaxf(((c0 + 1.f) * (float)H - 1.f) * 0.5f, 0.f), (float)(H - 1));
        float gx = fminf(fmaxf(((c1 + 1.f) * (float)W - 1.f) * 0.5f, 0.f), (float)(W - 1));
        int y0 = (int)floorf(gy); int x0 = (int)floorf(gx);
        int y1 = min(y0 + 1, H - 1); int x1 = min(x0 + 1, W - 1);
        const float wy = gy - (float)y0, wx = gx - (float)x0;
        const float* ip = img + ch * 4096;
        const float v00 = ip[y0 * 64 + x0], v01 = ip[y0 * 64 + x1];
        const float v10 = ip[y1 * 64 + x0], v11 = ip[y1 * 64 + x1];
        const float samp = v00 * (1.f - wy) * (1.f - wx) + v01 * (1.f - wy) * wx
                         + v10 * wy * (1.f - wx) + v11 * wy * wx;
        out[q * 3 + ch] = ret + samp;
    }
}

// =====================================================================
// FUSED FALLBACK (verbatim round-6 kernel, known-correct) — used if ws too small
// =====================================================================

#define LOADB2(dst, Wptr, kb) {                                                            \
    dst[0] = *(const bf16x8*)((Wptr) + (wc * 64 +      l31) * 256 + (kb) * 16 + hi8);      \
    dst[1] = *(const bf16x8*)((Wptr) + (wc * 64 + 32 + l31) * 256 + (kb) * 16 + hi8); }

__global__ __launch_bounds__(512, 4)
void lte_fused_kernel(const bf16_t* __restrict__ coefT,
                      const bf16_t* __restrict__ freqT,
                      const bf16_t* __restrict__ w1b,
                      const bf16_t* __restrict__ w2b,
                      const bf16_t* __restrict__ w3p,
                      const float4* __restrict__ wtab,
                      const float* __restrict__ img,
                      const float* __restrict__ coord,
                      const float* __restrict__ cell,
                      const float* __restrict__ b1,
                      const float* __restrict__ b2,
                      const float* __restrict__ b3,
                      float* __restrict__ out)
{
    extern __shared__ char smem[];
    bf16_t* buf    = (bf16_t*)smem;
    float*  areaS  = (float*)(smem + 67584);
    float*  predsS = (float*)(smem + 68096);

    const int t    = threadIdx.x;
    const int lane = t & 63;
    const int wv   = t >> 6;
    const int wr   = wv >> 2;
    const int wc   = wv & 3;
    const int l31  = lane & 31;
    const int hi8  = (lane >> 5) * 8;
    const int l15  = lane & 15;
    const int l16  = lane >> 4;

    {
        const int row = t >> 2;
        const int t4  = t & 3;
        const int qL  = row >> 2;
        const int o   = row & 3;
        const int q   = blockIdx.x * QPB + qL;
        const float c0  = coord[q * 2 + 0];
        const float c1  = coord[q * 2 + 1];
        const float rc0 = cell[q * 2 + 0] * (float)H;
        const float rc1 = cell[q * 2 + 1] * (float)W;
        const float vx = (o & 2) ? 1.f : -1.f;
        const float vy = (o & 1) ? 1.f : -1.f;
        const float EPS = 1e-6f;
        float g0 = fminf(fmaxf(c0 + vx * (1.f / H) + EPS, -1.f + EPS), 1.f - EPS);
        float g1 = fminf(fmaxf(c1 + vy * (1.f / W) + EPS, -1.f + EPS), 1.f - EPS);
        int iy = (int)floorf(((g0 + 1.f) * (float)H - 1.f) * 0.5f + 0.5f);
        iy = min(max(iy, 0), H - 1);
        int ix = (int)floorf(((g1 + 1.f) * (float)W - 1.f) * 0.5f + 0.5f);
        ix = min(max(ix, 0), W - 1);
        const float rel0 = (c0 - (-1.f + (2.f * (float)iy + 1.f) / (float)H)) * (float)H;
        const float rel1 = (c1 - (-1.f + (2.f * (float)ix + 1.f) / (float)W)) * (float)W;
        if (t4 == 0) areaS[row] = fabsf(rel0 * rel1) + 1e-9f;
        const int pix = iy * W + ix;
        const bf16_t* fq = freqT + pix * CF;
        const bf16_t* cf = coefT + pix * C;
        const int k0 = t4 * 32;

        bf16x8 fqv[4], ccv[4], csv[4];
#pragma unroll
        for (int i = 0; i < 4; i++) {
            fqv[i] = *(const bf16x8*)(fq + k0 + i * 8);
            ccv[i] = *(const bf16x8*)(cf + k0 + i * 8);
            csv[i] = *(const bf16x8*)(cf + 128 + k0 + i * 8);
        }
#pragma unroll
        for (int i = 0; i < 4; i++) {
            bf16x8 vc, vs;
#pragma unroll
            for (int j = 0; j < 8; j++) {
                const int k = k0 + i * 8 + j;
                const float4 tv = wtab[k];
                const float proj = rel0 * tv.x + rel1 * tv.y;
                const float ph   = rc0 * tv.z + rc1 * tv.w;
                const float m = (float)fqv[i][j] * proj + ph;
                float s, cst;
                __sincosf(PI_F * m, &s, &cst);
                vc[j] = (bf16_t)((float)ccv[i][j] * cst);
                vs[j] = (bf16_t)((float)csv[i][j] * s);
            }
            *(bf16x8*)(buf + (t >> 2) * PADC + k0 + i * 8)       = vc;
            *(bf16x8*)(buf + (t >> 2) * PADC + 128 + k0 + i * 8) = vs;
        }
    }

    bf16x8 bq[3][2];
    LOADB2(bq[0], w1b, 0);
    LOADB2(bq[1], w1b, 1);
    LOADB2(bq[2], w1b, 2);
    __syncthreads();

    bf16x8 cq[3][2];
    {
        f32x16 acc[2][2];
#pragma unroll
        for (int mi = 0; mi < 2; mi++)
#pragma unroll
            for (int nf = 0; nf < 2; nf++)
                acc[mi][nf] = (f32x16)(0.f);
#pragma unroll
        for (int kb = 0; kb < 16; kb++) {
            bf16x8 a[2];
#pragma unroll
            for (int mi = 0; mi < 2; mi++)
                a[mi] = *(bf16x8*)(buf + (wr * 64 + mi * 32 + l31) * PADC + kb * 16 + hi8);
#pragma unroll
            for (int mi = 0; mi < 2; mi++)
#pragma unroll
                for (int nf = 0; nf < 2; nf++)
                    acc[mi][nf] = __builtin_amdgcn_mfma_f32_32x32x16_bf16(a[mi], bq[kb % 3][nf], acc[mi][nf], 0, 0, 0);
            if (kb + 3 < 16) { LOADB2(bq[kb % 3], w1b, kb + 3); }
        }
        LOADB2(cq[0], w2b, 0);
        LOADB2(cq[1], w2b, 1);
        LOADB2(cq[2], w2b, 2);
        __syncthreads();
#pragma unroll
        for (int nf = 0; nf < 2; nf++) {
            const int col = wc * 64 + nf * 32 + l31;
            const float bv = b1[col];
#pragma unroll
            for (int mi = 0; mi < 2; mi++)
#pragma unroll
                for (int r = 0; r < 16; r++) {
                    const int row = wr * 64 + mi * 32 + (r & 3) + 8 * (r >> 2) + ((lane >> 5) * 4);
                    buf[row * PADC + col] = (bf16_t)fmaxf(acc[mi][nf][r] + bv, 0.f);
                }
        }
        __syncthreads();
    }

    {
        f32x16 acc[2][2];
#pragma unroll
        for (int mi = 0; mi < 2; mi++)
#pragma unroll
            for (int nf = 0; nf < 2; nf++)
                acc[mi][nf] = (f32x16)(0.f);
#pragma unroll
        for (int kb = 0; kb < 16; kb++) {
            bf16x8 a[2];
#pragma unroll
            for (int mi = 0; mi < 2; mi++)
                a[mi] = *(bf16x8*)(buf + (wr * 64 + mi * 32 + l31) * PADC + kb * 16 + hi8);
#pragma unroll
            for (int mi = 0; mi < 2; mi++)
#pragma unroll
                for (int nf = 0; nf < 2; nf++)
                    acc[mi][nf] = __builtin_amdgcn_mfma_f32_32x32x16_bf16(a[mi], cq[kb % 3][nf], acc[mi][nf], 0, 0, 0);
            if (kb + 3 < 16) { LOADB2(cq[kb % 3], w2b, kb + 3); }
        }
        __syncthreads();
#pragma unroll
        for (int nf = 0; nf < 2; nf++) {
            const int col = wc * 64 + nf * 32 + l31;
            const float bv = b2[col];
#pragma unroll
            for (int mi = 0; mi < 2; mi++)
#pragma unroll
                for (int r = 0; r < 16; r++) {
                    const int row = wr * 64 + mi * 32 + (r & 3) + 8 * (r >> 2) + ((lane >> 5) * 4);
                    buf[row * PADC + col] = (bf16_t)fmaxf(acc[mi][nf][r] + bv, 0.f);
                }
        }
        __syncthreads();
    }

    {
        f32x4 acc3 = {0.f, 0.f, 0.f, 0.f};
#pragma unroll
        for (int kb = 0; kb < 8; kb++) {
            bf16x8 a = *(bf16x8*)(buf + (wv * 16 + l15) * PADC + kb * 32 + l16 * 8);
            bf16x8 b = *(const bf16x8*)(w3p + l15 * 256 + kb * 32 + l16 * 8);
            acc3 = __builtin_amdgcn_mfma_f32_16x16x32_bf16(a, b, acc3, 0, 0, 0);
        }
        if (l15 < 3) {
            const float bv = b3[l15];
#pragma unroll
            for (int r = 0; r < 4; r++) {
                const int row = wv * 16 + l16 * 4 + r;
                predsS[row * 3 + l15] = acc3[r] + bv;
            }
        }
    }
    __syncthreads();

    if (t < QPB) {
        const int qL = t;
        const int q  = blockIdx.x * QPB + qL;
        const int r0 = qL * 4;
        const float a0 = areaS[r0 + 0], a1 = areaS[r0 + 1], a2 = areaS[r0 + 2], a3 = areaS[r0 + 3];
        const float inv = 1.f / (a0 + a1 + a2 + a3);
        const float wgt0 = a3 * inv, wgt1 = a2 * inv, wgt2 = a1 * inv, wgt3 = a0 * inv;
        const float c0 = coord[q * 2 + 0];
        const float c1 = coord[q * 2 + 1];
        float gy = fminf(fmaxf(((c0 + 1.f) * (float)H - 1.f) * 0.5f, 0.f), (float)(H - 1));
        float gx = fminf(fmaxf(((c1 + 1.f) * (float)W - 1.f) * 0.5f, 0.f), (float)(W - 1));
        int y0 = (int)floorf(gy); int x0 = (int)floorf(gx);
        int y1 = min(y0 + 1, H - 1); int x1 = min(x0 + 1, W - 1);
        const float wy = gy - (float)y0, wx = gx - (float)x0;
#pragma unroll
        for (int ch = 0; ch < 3; ch++) {
            const float ret = predsS[(r0 + 0) * 3 + ch] * wgt0 + predsS[(r0 + 1) * 3 + ch] * wgt1
                            + predsS[(r0 + 2) * 3 + ch] * wgt2 + predsS[(r0 + 3) * 3 + ch] * wgt3;
            const float* ip = img + ch * 4096;
            const float v00 = ip[y0 * 64 + x0], v01 = ip[y0 * 64 + x1];
            const float v10 = ip[y1 * 64 + x0], v11 = ip[y1 * 64 + x1];
            const float samp = v00 * (1.f - wy) * (1.f - wx) + v01 * (1.f - wy) * wx
                             + v10 * wy * (1.f - wx) + v11 * wy * wx;
            out[q * 3 + ch] = ret + samp;
        }
    }
}

// ---------------- launch ----------------

extern "C" void kernel_launch(void* const* d_in, const int* in_sizes, int n_in,
                              void* d_out, int out_size, void* d_ws, size_t ws_size,
                              hipStream_t stream) {
    const float* img   = (const float*)d_in[0];
    const float* coef  = (const float*)d_in[1];
    const float* freq  = (const float*)d_in[2];
    const float* coord = (const float*)d_in[3];
    const float* cell  = (const float*)d_in[4];
    const float* wcf   = (const float*)d_in[5];
    const float* wph   = (const float*)d_in[6];
    const float* w1    = (const float*)d_in[7];
    const float* b1    = (const float*)d_in[8];
    const float* w2    = (const float*)d_in[9];
    const float* b2    = (const float*)d_in[10];
    const float* w3    = (const float*)d_in[11];
    const float* b3    = (const float*)d_in[12];
    float* out = (float*)d_out;

    char* ws = (char*)d_ws;
    bf16_t* coefT = (bf16_t*)ws;                  // 2,097,152
    bf16_t* freqT = (bf16_t*)(ws + 2097152);      // 1,048,576
    bf16_t* w1b   = (bf16_t*)(ws + 3145728);      // 131,072
    bf16_t* w2b   = (bf16_t*)(ws + 3276800);      // 131,072
    float4* wtab  = (float4*)(ws + 3407872);      // 2,048
    bf16_t* w3p   = (bf16_t*)(ws + 3409920);      // 8,192
    float*  areaW = (float*)(ws + 3418112);       // 1,048,576
    char*   xf    = ws + 4466688;                 // 134,217,728 (512-aligned)
    const size_t WS_NEED = 4466688u + (size_t)MROWS * 512u;  // 138,684,416

    transpose_cvt_kernel<<<dim3(128, 8), 256, 0, stream>>>(coef, coefT, 256);
    transpose_cvt_kernel<<<dim3(128, 4), 256, 0, stream>>>(freq, freqT, 128);
    cvt_w_kernel<<<256, 256, 0, stream>>>(w1, w2, w1b, w2b);
    pack_tab_kernel<<<1, 128, 0, stream>>>(wcf, wph, wtab);
    cvt_w3_kernel<<<1, 256, 0, stream>>>(w3, w3p);

    if (ws_size >= WS_NEED) {
        // split path: barrier-free feature kernel + staged GEMM kernel
        feat_kernel<<<MROWS / 64, 256, 0, stream>>>(coefT, freqT, wtab, coord, cell, xf, areaW);
        const size_t ldsBytes = 65536 + 1536;
        mlp_kernel<<<MROWS / 128, 512, ldsBytes, stream>>>(
            xf, w1b, w2b, w3p, areaW, img, coord, b1, b2, b3, out);
    } else {
        // fallback: fused single kernel (round-6, known-correct)
        const size_t ldsBytes = 69632;
        lte_fused_kernel<<<Q / QPB, 512, ldsBytes, stream>>>(
            coefT, freqT, w1b, w2b, w3p, wtab, img, coord, cell, b1, b2, b3, out);
    }
}

// Round 8
// 240.661 us; speedup vs baseline: 1.3701x; 1.3701x over previous
//
#include <hip/hip_runtime.h>
#include <math.h>

typedef __bf16 bf16_t;
typedef bf16_t bf16x8 __attribute__((ext_vector_type(8)));
typedef float  f32x4  __attribute__((ext_vector_type(4)));

#define PI_F 3.14159265358979323846f

constexpr int H = 64, W = 64, Q = 65536;
constexpr int C = 256, CF = 128;
constexpr int ROWS_T = 64;     // rows per tile (16 queries x 4 offsets)
constexpr int QPT = 16;        // queries per tile
constexpr int T_TILES = 4;     // tiles per block
constexpr int PADC = 264;      // LDS row stride (bf16)

// ---------------- prep kernels ----------------

__global__ void transpose_cvt_kernel(const float* __restrict__ src, bf16_t* __restrict__ dst, int Crows) {
    __shared__ float tile[32][33];
    int bx = blockIdx.x * 32;
    int by = blockIdx.y * 32;
    int tx = threadIdx.x & 31;
    int ty = threadIdx.x >> 5;
#pragma unroll
    for (int i = 0; i < 4; i++)
        tile[ty + i * 8][tx] = src[(by + ty + i * 8) * 4096 + bx + tx];
    __syncthreads();
#pragma unroll
    for (int i = 0; i < 4; i++)
        dst[(bx + ty + i * 8) * Crows + by + tx] = (bf16_t)tile[tx][ty + i * 8];
}

__global__ void cvt_w_kernel(const float* __restrict__ w1, const float* __restrict__ w2,
                             bf16_t* __restrict__ w1b, bf16_t* __restrict__ w2b) {
    int i = blockIdx.x * 256 + threadIdx.x;
    w1b[i] = (bf16_t)w1[i];
    w2b[i] = (bf16_t)w2[i];
}

__global__ void pack_tab_kernel(const float* __restrict__ wcf, const float* __restrict__ wph,
                                float4* __restrict__ wtab) {
    int k = threadIdx.x;
    float4 v;
    v.x = wcf[k * 2 + 0]; v.y = wcf[k * 2 + 1];
    v.z = wph[k * 2 + 0]; v.w = wph[k * 2 + 1];
    wtab[k] = v;
}

// w3 [3][256] -> w3p [16][256] bf16, rows 3..15 zero
__global__ void cvt_w3_kernel(const float* __restrict__ w3, bf16_t* __restrict__ w3p) {
    int k = threadIdx.x;
#pragma unroll
    for (int n = 0; n < 16; n++)
        w3p[n * 256 + k] = (n < 3) ? (bf16_t)w3[n * 256 + k] : (bf16_t)0.f;
}

// ---------------- main kernel: persistent tile pipeline ----------------

// one 64x256 * 256x256 layer: MFMA + relu writeback into bufcur. 2 internal barriers.
__device__ __forceinline__ void gemm_layer(const bf16_t* __restrict__ Wg,
                                           const float* __restrict__ bg,
                                           bf16_t* bufcur,
                                           int wv, int l15, int l16) {
#define BLOAD(slot, kb) {                                                                       \
    bq[slot][0] = *(const bf16x8*)(Wg + (wv * 32 +      l15) * 256 + (kb) * 32 + l16 * 8);      \
    bq[slot][1] = *(const bf16x8*)(Wg + (wv * 32 + 16 + l15) * 256 + (kb) * 32 + l16 * 8); }
    f32x4 acc[4][2];
#pragma unroll
    for (int mi = 0; mi < 4; mi++)
#pragma unroll
        for (int nf = 0; nf < 2; nf++) {
            f32x4 z = {0.f, 0.f, 0.f, 0.f};
            acc[mi][nf] = z;
        }
    bf16x8 bq[2][2];
    BLOAD(0, 0);
    BLOAD(1, 1);
#pragma unroll
    for (int kb = 0; kb < 8; kb++) {
        bf16x8 a[4];
#pragma unroll
        for (int mi = 0; mi < 4; mi++)
            a[mi] = *(bf16x8*)(bufcur + (mi * 16 + l15) * PADC + kb * 32 + l16 * 8);
#pragma unroll
        for (int mi = 0; mi < 4; mi++)
#pragma unroll
            for (int nf = 0; nf < 2; nf++)
                acc[mi][nf] = __builtin_amdgcn_mfma_f32_16x16x32_bf16(a[mi], bq[kb & 1][nf], acc[mi][nf], 0, 0, 0);
        if (kb + 2 < 8) { BLOAD(kb & 1, kb + 2); }
    }
    __syncthreads();  // all A reads done
#pragma unroll
    for (int nf = 0; nf < 2; nf++) {
        const int col = wv * 32 + nf * 16 + l15;
        const float bv = bg[col];
#pragma unroll
        for (int mi = 0; mi < 4; mi++)
#pragma unroll
            for (int r = 0; r < 4; r++) {
                const int row = mi * 16 + l16 * 4 + r;
                bufcur[row * PADC + col] = (bf16_t)fmaxf(acc[mi][nf][r] + bv, 0.f);
            }
    }
    __syncthreads();  // h visible
#undef BLOAD
}

__global__ __launch_bounds__(512, 4)
void lte_pipe_kernel(const bf16_t* __restrict__ coefT,  // [4096][256]
                     const bf16_t* __restrict__ freqT,  // [4096][128]
                     const bf16_t* __restrict__ w1b,
                     const bf16_t* __restrict__ w2b,
                     const bf16_t* __restrict__ w3p,    // [16][256]
                     const float4* __restrict__ wtab,   // [128]
                     const float* __restrict__ img,
                     const float* __restrict__ coord,
                     const float* __restrict__ cell,
                     const float* __restrict__ b1,
                     const float* __restrict__ b2,
                     const float* __restrict__ b3,
                     float* __restrict__ out)
{
    extern __shared__ char smem[];
    bf16_t* buf0   = (bf16_t*)smem;                  // [64][264] (33792 B)
    bf16_t* buf1   = (bf16_t*)(smem + 33792);        // [64][264]
    float4* wtabS  = (float4*)(smem + 67584);        // [128]  (2048 B)
    float*  areaS  = (float*)(smem + 69632);         // [2][64]
    float*  predsS = (float*)(smem + 70144);         // [64][3]

    const int t    = threadIdx.x;
    const int lane = t & 63;
    const int wv   = t >> 6;     // 0..7 -> 32-col stripe in layers 1/2
    const int l15  = lane & 15;
    const int l16  = lane >> 4;
    const int row  = t >> 3;     // 0..63  (stage/area mapping: 8 thr/row)
    const int t8   = t & 7;
    const int k0   = t8 * 16;

    const int tile0 = blockIdx.x * T_TILES;

    // ---- persistent stage state (registers) ----
    bf16x8 fqv[2], ccv[2], csv[2];
    float rel0, rel1, rc0, rc1, areaR;

    // issue gathers + geometry for tile `tl` into registers
    auto issue_gathers = [&](int tl) {
        const int q = tl * QPT + (row >> 2);
        const int o = row & 3;
        const float c0 = coord[q * 2 + 0];
        const float c1 = coord[q * 2 + 1];
        rc0 = cell[q * 2 + 0] * (float)H;
        rc1 = cell[q * 2 + 1] * (float)W;
        const float vx = (o & 2) ? 1.f : -1.f;
        const float vy = (o & 1) ? 1.f : -1.f;
        const float EPS = 1e-6f;
        float g0 = fminf(fmaxf(c0 + vx * (1.f / H) + EPS, -1.f + EPS), 1.f - EPS);
        float g1 = fminf(fmaxf(c1 + vy * (1.f / W) + EPS, -1.f + EPS), 1.f - EPS);
        int iy = (int)floorf(((g0 + 1.f) * (float)H - 1.f) * 0.5f + 0.5f);
        iy = min(max(iy, 0), H - 1);
        int ix = (int)floorf(((g1 + 1.f) * (float)W - 1.f) * 0.5f + 0.5f);
        ix = min(max(ix, 0), W - 1);
        rel0 = (c0 - (-1.f + (2.f * (float)iy + 1.f) / (float)H)) * (float)H;
        rel1 = (c1 - (-1.f + (2.f * (float)ix + 1.f) / (float)W)) * (float)W;
        areaR = fabsf(rel0 * rel1) + 1e-9f;
        const int pix = iy * W + ix;
        const bf16_t* fq = freqT + pix * CF;
        const bf16_t* cf = coefT + pix * C;
#pragma unroll
        for (int i = 0; i < 2; i++) {
            fqv[i] = *(const bf16x8*)(fq + k0 + i * 8);
            ccv[i] = *(const bf16x8*)(cf + k0 + i * 8);
            csv[i] = *(const bf16x8*)(cf + 128 + k0 + i * 8);
        }
    };

    // trig + write X into dst buffer (consumes the gathered regs)
    auto finish_stage = [&](bf16_t* dst, float* areaDst) {
        if (t8 == 0) areaDst[row] = areaR;
#pragma unroll
        for (int i = 0; i < 2; i++) {
            bf16x8 vc, vs;
#pragma unroll
            for (int j = 0; j < 8; j++) {
                const int k = k0 + i * 8 + j;
                const float4 tv = wtabS[k];
                const float proj = rel0 * tv.x + rel1 * tv.y;
                const float ph   = rc0 * tv.z + rc1 * tv.w;
                const float m = (float)fqv[i][j] * proj + ph;
                float s, cst;
                __sincosf(PI_F * m, &s, &cst);
                vc[j] = (bf16_t)((float)ccv[i][j] * cst);
                vs[j] = (bf16_t)((float)csv[i][j] * s);
            }
            *(bf16x8*)(dst + row * PADC + k0 + i * 8)       = vc;
            *(bf16x8*)(dst + row * PADC + 128 + k0 + i * 8) = vs;
        }
    };

    // ---- prologue ----
    if (t < 128) wtabS[t] = wtab[t];
    issue_gathers(tile0);
    __syncthreads();                 // wtabS visible
    finish_stage(buf0, areaS);       // X(tile0) -> buf0
    __syncthreads();

    int cur = 0;
#pragma unroll 1
    for (int tt = 0; tt < T_TILES; tt++) {
        const int tile = tile0 + tt;
        bf16_t* bc = cur ? buf1 : buf0;
        bf16_t* bn = cur ? buf0 : buf1;

        if (tt + 1 < T_TILES) issue_gathers(tile + 1);  // VMEM in flight over layer 1

        gemm_layer(w1b, b1, bc, wv, l15, l16);  // X -> h1 (2 barriers inside)
        gemm_layer(w2b, b2, bc, wv, l15, l16);  // h1 -> h2

        // layer 3 on waves 0..3; stage next tile on all waves
        if (wv < 4) {
            f32x4 acc3 = {0.f, 0.f, 0.f, 0.f};
#pragma unroll
            for (int kb = 0; kb < 8; kb++) {
                bf16x8 a = *(bf16x8*)(bc + (wv * 16 + l15) * PADC + kb * 32 + l16 * 8);
                bf16x8 b = *(const bf16x8*)(w3p + l15 * 256 + kb * 32 + l16 * 8);
                acc3 = __builtin_amdgcn_mfma_f32_16x16x32_bf16(a, b, acc3, 0, 0, 0);
            }
            if (l15 < 3) {
                const float bv = b3[l15];
#pragma unroll
                for (int r = 0; r < 4; r++)
                    predsS[(wv * 16 + l16 * 4 + r) * 3 + l15] = acc3[r] + bv;
            }
        }
        if (tt + 1 < T_TILES) finish_stage(bn, areaS + (cur ^ 1) * 64);
        __syncthreads();  // preds + X(t+1) visible

        // combine: 48 threads, one per (query, channel)
        if (t < 48) {
            const int ch = t >> 4;
            const int qL = t & 15;
            const int q  = tile * QPT + qL;
            const int r0 = qL * 4;
            const float* ar = areaS + cur * 64;
            const float a0 = ar[r0 + 0], a1 = ar[r0 + 1], a2 = ar[r0 + 2], a3 = ar[r0 + 3];
            const float inv = 1.f / (a0 + a1 + a2 + a3);
            const float wgt0 = a3 * inv, wgt1 = a2 * inv, wgt2 = a1 * inv, wgt3 = a0 * inv;
            const float ret = predsS[(r0 + 0) * 3 + ch] * wgt0 + predsS[(r0 + 1) * 3 + ch] * wgt1
                            + predsS[(r0 + 2) * 3 + ch] * wgt2 + predsS[(r0 + 3) * 3 + ch] * wgt3;
            const float c0 = coord[q * 2 + 0];
            const float c1 = coord[q * 2 + 1];
            float gy = fminf(fmaxf(((c0 + 1.f) * (float)H - 1.f) * 0.5f, 0.f), (float)(H - 1));
            float gx = fminf(fmaxf(((c1 + 1.f) * (float)W - 1.f) * 0.5f, 0.f), (float)(W - 1));
            int y0 = (int)floorf(gy); int x0 = (int)floorf(gx);
            int y1 = min(y0 + 1, H - 1); int x1 = min(x0 + 1, W - 1);
            const float wy = gy - (float)y0, wx = gx - (float)x0;
            const float* ip = img + ch * 4096;
            const float v00 = ip[y0 * 64 + x0], v01 = ip[y0 * 64 + x1];
            const float v10 = ip[y1 * 64 + x0], v11 = ip[y1 * 64 + x1];
            const float samp = v00 * (1.f - wy) * (1.f - wx) + v01 * (1.f - wy) * wx
                             + v10 * wy * (1.f - wx) + v11 * wy * wx;
            out[q * 3 + ch] = ret + samp;
        }
        cur ^= 1;
    }
}

// ---------------- launch ----------------

extern "C" void kernel_launch(void* const* d_in, const int* in_sizes, int n_in,
                              void* d_out, int out_size, void* d_ws, size_t ws_size,
                              hipStream_t stream) {
    const float* img   = (const float*)d_in[0];
    const float* coef  = (const float*)d_in[1];
    const float* freq  = (const float*)d_in[2];
    const float* coord = (const float*)d_in[3];
    const float* cell  = (const float*)d_in[4];
    const float* wcf   = (const float*)d_in[5];
    const float* wph   = (const float*)d_in[6];
    const float* w1    = (const float*)d_in[7];
    const float* b1    = (const float*)d_in[8];
    const float* w2    = (const float*)d_in[9];
    const float* b2    = (const float*)d_in[10];
    const float* w3    = (const float*)d_in[11];
    const float* b3    = (const float*)d_in[12];
    float* out = (float*)d_out;

    char* ws = (char*)d_ws;
    bf16_t* coefT = (bf16_t*)ws;                  // 2,097,152
    bf16_t* freqT = (bf16_t*)(ws + 2097152);      // 1,048,576
    bf16_t* w1b   = (bf16_t*)(ws + 3145728);      // 131,072
    bf16_t* w2b   = (bf16_t*)(ws + 3276800);      // 131,072
    float4* wtab  = (float4*)(ws + 3407872);      // 2,048
    bf16_t* w3p   = (bf16_t*)(ws + 3409920);      // 8,192

    transpose_cvt_kernel<<<dim3(128, 8), 256, 0, stream>>>(coef, coefT, 256);
    transpose_cvt_kernel<<<dim3(128, 4), 256, 0, stream>>>(freq, freqT, 128);
    cvt_w_kernel<<<256, 256, 0, stream>>>(w1, w2, w1b, w2b);
    pack_tab_kernel<<<1, 128, 0, stream>>>(wcf, wph, wtab);
    cvt_w3_kernel<<<1, 256, 0, stream>>>(w3, w3p);

    // 1024 blocks x 4 tiles x 64 rows = 262144 rows
    const size_t ldsBytes = 70912;  // 2x33792 buf + 2048 wtab + 512 area + 768 preds
    lte_pipe_kernel<<<(Q * 4) / (ROWS_T * T_TILES), 512, ldsBytes, stream>>>(
        coefT, freqT, w1b, w2b, w3p, wtab, img, coord, cell, b1, b2, b3, out);
}

// Round 9
// 170.973 us; speedup vs baseline: 1.9285x; 1.4076x over previous
//
#include <hip/hip_runtime.h>
#include <math.h>

typedef __bf16 bf16_t;
typedef bf16_t bf16x8 __attribute__((ext_vector_type(8)));
typedef float  f32x4  __attribute__((ext_vector_type(4)));

constexpr int H = 64, W = 64, Q = 65536;
constexpr int C = 256, CF = 128;
constexpr int QPB = 32;        // queries per block -> 2048 blocks
constexpr int PADC = 264;      // LDS row stride (bf16)

// ---------------- prep kernels ----------------

// src [Crows][4096] f32 -> dst [4096][Crows] bf16  (pixel-major, L2-resident gathers)
__global__ void transpose_cvt_kernel(const float* __restrict__ src, bf16_t* __restrict__ dst, int Crows) {
    __shared__ float tile[32][33];
    int bx = blockIdx.x * 32;
    int by = blockIdx.y * 32;
    int tx = threadIdx.x & 31;
    int ty = threadIdx.x >> 5;
#pragma unroll
    for (int i = 0; i < 4; i++)
        tile[ty + i * 8][tx] = src[(by + ty + i * 8) * 4096 + bx + tx];
    __syncthreads();
#pragma unroll
    for (int i = 0; i < 4; i++)
        dst[(bx + ty + i * 8) * Crows + by + tx] = (bf16_t)tile[tx][ty + i * 8];
}

__global__ void cvt_w_kernel(const float* __restrict__ w1, const float* __restrict__ w2,
                             bf16_t* __restrict__ w1b, bf16_t* __restrict__ w2b) {
    int i = blockIdx.x * 256 + threadIdx.x;
    w1b[i] = (bf16_t)w1[i];
    w2b[i] = (bf16_t)w2[i];
}

__global__ void pack_tab_kernel(const float* __restrict__ wcf, const float* __restrict__ wph,
                                float4* __restrict__ wtab) {
    int k = threadIdx.x;
    float4 v;
    v.x = wcf[k * 2 + 0]; v.y = wcf[k * 2 + 1];
    v.z = wph[k * 2 + 0]; v.w = wph[k * 2 + 1];
    wtab[k] = v;
}

// w3 [3][256] -> w3p [16][256] bf16, rows 3..15 zero
__global__ void cvt_w3_kernel(const float* __restrict__ w3, bf16_t* __restrict__ w3p) {
    int k = threadIdx.x;
#pragma unroll
    for (int n = 0; n < 16; n++)
        w3p[n * 256 + k] = (n < 3) ? (bf16_t)w3[n * 256 + k] : (bf16_t)0.f;
}

// ---------------- fused main kernel (R4 structure) ----------------

// load the wave's 2 B-fragments for k-block kb
#define LOADB(dst, Wptr, kb)                                                                  \
    {                                                                                         \
        dst[0] = *(const bf16x8*)((Wptr) + (wv * 32 + l15) * 256 + (kb) * 32 + l16 * 8);      \
        dst[1] = *(const bf16x8*)((Wptr) + (wv * 32 + 16 + l15) * 256 + (kb) * 32 + l16 * 8); \
    }

__global__ __launch_bounds__(512, 4)
void lte_fused_kernel(const bf16_t* __restrict__ coefT,  // [4096][256] bf16
                      const bf16_t* __restrict__ freqT,  // [4096][128] bf16
                      const bf16_t* __restrict__ w1b,    // [256][256] (out,in)
                      const bf16_t* __restrict__ w2b,
                      const bf16_t* __restrict__ w3p,    // [16][256] padded bf16
                      const float4* __restrict__ wtab,   // [128] packed (wcf0,wcf1,wph0,wph1)
                      const float* __restrict__ img,     // [3][64][64]
                      const float* __restrict__ coord,   // [Q][2]
                      const float* __restrict__ cell,    // [Q][2]
                      const float* __restrict__ b1,
                      const float* __restrict__ b2,
                      const float* __restrict__ b3,
                      float* __restrict__ out)           // [Q][3]
{
    extern __shared__ char smem[];
    bf16_t* buf    = (bf16_t*)smem;              // [128][264] bf16: X -> h1 -> h2 (67584 B)
    float*  areaS  = (float*)(smem + 67584);     // [128]
    float*  predsS = (float*)(smem + 68096);     // [128][3]

    const int t    = threadIdx.x;
    const int lane = t & 63;
    const int wv   = t >> 6;     // wave id 0..7 -> 32-col stripe
    const int l15  = lane & 15;
    const int l16  = lane >> 4;

    // ---- stage 1: features -> X (bf16) in LDS. 4 threads/row, 32 k each ----
    {
        const int row = t >> 2;   // 0..127
        const int t4  = t & 3;
        const int qL  = row >> 2;
        const int o   = row & 3;
        const int q   = blockIdx.x * QPB + qL;
        const float c0  = coord[q * 2 + 0];
        const float c1  = coord[q * 2 + 1];
        const float rc0 = cell[q * 2 + 0] * (float)H;
        const float rc1 = cell[q * 2 + 1] * (float)W;
        const float vx = (o & 2) ? 1.f : -1.f;
        const float vy = (o & 1) ? 1.f : -1.f;
        const float EPS = 1e-6f;
        float g0 = fminf(fmaxf(c0 + vx * (1.f / H) + EPS, -1.f + EPS), 1.f - EPS);
        float g1 = fminf(fmaxf(c1 + vy * (1.f / W) + EPS, -1.f + EPS), 1.f - EPS);
        int iy = (int)floorf(((g0 + 1.f) * (float)H - 1.f) * 0.5f + 0.5f);
        iy = min(max(iy, 0), H - 1);
        int ix = (int)floorf(((g1 + 1.f) * (float)W - 1.f) * 0.5f + 0.5f);
        ix = min(max(ix, 0), W - 1);
        const float rel0 = (c0 - (-1.f + (2.f * (float)iy + 1.f) / (float)H)) * (float)H;
        const float rel1 = (c1 - (-1.f + (2.f * (float)ix + 1.f) / (float)W)) * (float)W;
        if (t4 == 0) areaS[row] = fabsf(rel0 * rel1) + 1e-9f;
        const int pix = iy * W + ix;
        const bf16_t* fq = freqT + pix * CF;
        const bf16_t* cf = coefT + pix * C;
        const int k0 = t4 * 32;

        // issue ALL gathers up front (12 x 16B)
        bf16x8 fqv[4], ccv[4], csv[4];
#pragma unroll
        for (int i = 0; i < 4; i++) {
            fqv[i] = *(const bf16x8*)(fq + k0 + i * 8);
            ccv[i] = *(const bf16x8*)(cf + k0 + i * 8);
            csv[i] = *(const bf16x8*)(cf + 128 + k0 + i * 8);
        }
#pragma unroll
        for (int i = 0; i < 4; i++) {
            bf16x8 vc, vs;
#pragma unroll
            for (int j = 0; j < 8; j++) {
                const int k = k0 + i * 8 + j;
                const float4 tv = wtab[k];
                const float proj = rel0 * tv.x + rel1 * tv.y;
                const float ph   = rc0 * tv.z + rc1 * tv.w;
                const float m = (float)fqv[i][j] * proj + ph;
                // sin(pi*m) = sin(2*pi*fract(m/2)) -- native HW trig (v_fract+v_sin/v_cos)
                const float xr  = __builtin_amdgcn_fractf(m * 0.5f);
                const float s   = __builtin_amdgcn_sinf(xr);
                const float cst = __builtin_amdgcn_cosf(xr);
                vc[j] = (bf16_t)((float)ccv[i][j] * cst);
                vs[j] = (bf16_t)((float)csv[i][j] * s);
            }
            *(bf16x8*)(buf + row * PADC + k0 + i * 8)       = vc;
            *(bf16x8*)(buf + row * PADC + 128 + k0 + i * 8) = vs;
        }
    }

    // prefetch layer-1 B fragments for kb=0,1 BEFORE the barrier
    bf16x8 b1q[8][2];
    LOADB(b1q[0], w1b, 0);
    LOADB(b1q[1], w1b, 1);
    __syncthreads();

    // ---- layer 1: MFMA, wave = 128 rows x 32-col stripe, register B-queue ----
    bf16x8 b2q[8][2];
    {
        f32x4 acc[8][2];
#pragma unroll
        for (int mi = 0; mi < 8; mi++)
#pragma unroll
            for (int nf = 0; nf < 2; nf++) {
                f32x4 z = {0.f, 0.f, 0.f, 0.f};
                acc[mi][nf] = z;
            }
#pragma unroll
        for (int kb = 0; kb < 8; kb++) {
            if (kb < 6) { LOADB(b1q[kb + 2], w1b, kb + 2); }
            bf16x8 a[8];
#pragma unroll
            for (int mi = 0; mi < 8; mi++)
                a[mi] = *(bf16x8*)(buf + (mi * 16 + l15) * PADC + kb * 32 + l16 * 8);
#pragma unroll
            for (int mi = 0; mi < 8; mi++)
#pragma unroll
                for (int nf = 0; nf < 2; nf++)
                    acc[mi][nf] = __builtin_amdgcn_mfma_f32_16x16x32_bf16(a[mi], b1q[kb][nf], acc[mi][nf], 0, 0, 0);
        }
        // prefetch layer-2 kb=0,1 before the barrier
        LOADB(b2q[0], w2b, 0);
        LOADB(b2q[1], w2b, 1);
        __syncthreads();  // all reads of X done
#pragma unroll
        for (int nf = 0; nf < 2; nf++) {
            const int col = wv * 32 + nf * 16 + l15;
            const float bv = b1[col];
#pragma unroll
            for (int mi = 0; mi < 8; mi++)
#pragma unroll
                for (int r = 0; r < 4; r++) {
                    const int row = mi * 16 + l16 * 4 + r;
                    buf[row * PADC + col] = (bf16_t)fmaxf(acc[mi][nf][r] + bv, 0.f);
                }
        }
        __syncthreads();
    }

    // ---- layer 2 ----
    {
        f32x4 acc[8][2];
#pragma unroll
        for (int mi = 0; mi < 8; mi++)
#pragma unroll
            for (int nf = 0; nf < 2; nf++) {
                f32x4 z = {0.f, 0.f, 0.f, 0.f};
                acc[mi][nf] = z;
            }
#pragma unroll
        for (int kb = 0; kb < 8; kb++) {
            if (kb < 6) { LOADB(b2q[kb + 2], w2b, kb + 2); }
            bf16x8 a[8];
#pragma unroll
            for (int mi = 0; mi < 8; mi++)
                a[mi] = *(bf16x8*)(buf + (mi * 16 + l15) * PADC + kb * 32 + l16 * 8);
#pragma unroll
            for (int mi = 0; mi < 8; mi++)
#pragma unroll
                for (int nf = 0; nf < 2; nf++)
                    acc[mi][nf] = __builtin_amdgcn_mfma_f32_16x16x32_bf16(a[mi], b2q[kb][nf], acc[mi][nf], 0, 0, 0);
        }
        __syncthreads();  // all reads of h1 done
#pragma unroll
        for (int nf = 0; nf < 2; nf++) {
            const int col = wv * 32 + nf * 16 + l15;
            const float bv = b2[col];
#pragma unroll
            for (int mi = 0; mi < 8; mi++)
#pragma unroll
                for (int r = 0; r < 4; r++) {
                    const int row = mi * 16 + l16 * 4 + r;
                    buf[row * PADC + col] = (bf16_t)fmaxf(acc[mi][nf][r] + bv, 0.f);
                }
        }
        __syncthreads();
    }

    // ---- layer 3: MFMA vs padded w3 (conflict-free). wave wv = rows wv*16.. ----
    {
        f32x4 acc3 = {0.f, 0.f, 0.f, 0.f};
#pragma unroll
        for (int kb = 0; kb < 8; kb++) {
            bf16x8 a = *(bf16x8*)(buf + (wv * 16 + l15) * PADC + kb * 32 + l16 * 8);
            bf16x8 b = *(const bf16x8*)(w3p + l15 * 256 + kb * 32 + l16 * 8);
            acc3 = __builtin_amdgcn_mfma_f32_16x16x32_bf16(a, b, acc3, 0, 0, 0);
        }
        if (l15 < 3) {
            const float bv = b3[l15];
#pragma unroll
            for (int r = 0; r < 4; r++) {
                const int row = wv * 16 + l16 * 4 + r;
                predsS[row * 3 + l15] = acc3[r] + bv;
            }
        }
    }
    __syncthreads();

    // ---- combine: area weights (reversed) + bilinear border sample ----
    if (t < QPB) {
        const int qL = t;
        const int q  = blockIdx.x * QPB + qL;
        const int r0 = qL * 4;
        const float a0 = areaS[r0 + 0], a1 = areaS[r0 + 1], a2 = areaS[r0 + 2], a3 = areaS[r0 + 3];
        const float inv = 1.f / (a0 + a1 + a2 + a3);
        const float wgt0 = a3 * inv, wgt1 = a2 * inv, wgt2 = a1 * inv, wgt3 = a0 * inv;
        const float c0 = coord[q * 2 + 0];
        const float c1 = coord[q * 2 + 1];
        float gy = fminf(fmaxf(((c0 + 1.f) * (float)H - 1.f) * 0.5f, 0.f), (float)(H - 1));
        float gx = fminf(fmaxf(((c1 + 1.f) * (float)W - 1.f) * 0.5f, 0.f), (float)(W - 1));
        int y0 = (int)floorf(gy); int x0 = (int)floorf(gx);
        int y1 = min(y0 + 1, H - 1); int x1 = min(x0 + 1, W - 1);
        const float wy = gy - (float)y0, wx = gx - (float)x0;
#pragma unroll
        for (int ch = 0; ch < 3; ch++) {
            const float ret = predsS[(r0 + 0) * 3 + ch] * wgt0 + predsS[(r0 + 1) * 3 + ch] * wgt1
                            + predsS[(r0 + 2) * 3 + ch] * wgt2 + predsS[(r0 + 3) * 3 + ch] * wgt3;
            const float* ip = img + ch * 4096;
            const float v00 = ip[y0 * 64 + x0], v01 = ip[y0 * 64 + x1];
            const float v10 = ip[y1 * 64 + x0], v11 = ip[y1 * 64 + x1];
            const float samp = v00 * (1.f - wy) * (1.f - wx) + v01 * (1.f - wy) * wx
                             + v10 * wy * (1.f - wx) + v11 * wy * wx;
            out[q * 3 + ch] = ret + samp;
        }
    }
}

// ---------------- launch ----------------

extern "C" void kernel_launch(void* const* d_in, const int* in_sizes, int n_in,
                              void* d_out, int out_size, void* d_ws, size_t ws_size,
                              hipStream_t stream) {
    const float* img   = (const float*)d_in[0];
    const float* coef  = (const float*)d_in[1];
    const float* freq  = (const float*)d_in[2];
    const float* coord = (const float*)d_in[3];
    const float* cell  = (const float*)d_in[4];
    const float* wcf   = (const float*)d_in[5];
    const float* wph   = (const float*)d_in[6];
    const float* w1    = (const float*)d_in[7];
    const float* b1    = (const float*)d_in[8];
    const float* w2    = (const float*)d_in[9];
    const float* b2    = (const float*)d_in[10];
    const float* w3    = (const float*)d_in[11];
    const float* b3    = (const float*)d_in[12];
    float* out = (float*)d_out;

    char* ws = (char*)d_ws;
    bf16_t* coefT = (bf16_t*)ws;                  // 2,097,152
    bf16_t* freqT = (bf16_t*)(ws + 2097152);      // 1,048,576
    bf16_t* w1b   = (bf16_t*)(ws + 3145728);      // 131,072
    bf16_t* w2b   = (bf16_t*)(ws + 3276800);      // 131,072
    float4* wtab  = (float4*)(ws + 3407872);      // 2,048
    bf16_t* w3p   = (bf16_t*)(ws + 3409920);      // 8,192

    transpose_cvt_kernel<<<dim3(128, 8), 256, 0, stream>>>(coef, coefT, 256);
    transpose_cvt_kernel<<<dim3(128, 4), 256, 0, stream>>>(freq, freqT, 128);
    cvt_w_kernel<<<256, 256, 0, stream>>>(w1, w2, w1b, w2b);
    pack_tab_kernel<<<1, 128, 0, stream>>>(wcf, wph, wtab);
    cvt_w3_kernel<<<1, 256, 0, stream>>>(w3, w3p);

    const size_t ldsBytes = 69632;  // 67584 buf + 512 area + 1536 preds
    lte_fused_kernel<<<Q / QPB, 512, ldsBytes, stream>>>(
        coefT, freqT, w1b, w2b, w3p, wtab, img, coord, cell, b1, b2, b3, out);
}